// Round 1
// baseline (681.085 us; speedup 1.0000x reference)
//
#include <hip/hip_runtime.h>
#include <stdint.h>

#define N_TOK   4096
#define DMODEL  1024
#define DFF     2048
#define N_EXP   8
#define N_SLOTS (N_TOK * 2)        // 8192 (every token has exactly 2 expert slots)
#define ROWS_PAD (N_SLOTS + 128)   // padding so tile-tail OOB reads stay in-bounds

typedef __bf16 bf16x8 __attribute__((ext_vector_type(8)));
typedef float  f32x4  __attribute__((ext_vector_type(4)));
typedef unsigned short u16;
typedef unsigned short u16x8 __attribute__((ext_vector_type(8)));
typedef unsigned short u16x4 __attribute__((ext_vector_type(4)));

__device__ __forceinline__ u16 f2bf(float f) {
    union { float f; uint32_t u; } v; v.f = f;
    uint32_t r = v.u + 0x7FFFu + ((v.u >> 16) & 1u);  // RTNE
    return (u16)(r >> 16);
}

// async 16B/lane global->LDS. LDS dest is wave-uniform base + lane*16 (m104 caveat).
__device__ __forceinline__ void g2l16(const void* gp, void* lp) {
    auto g = reinterpret_cast<const __attribute__((address_space(1))) unsigned int*>(
        reinterpret_cast<uintptr_t>(gp));
    auto l = reinterpret_cast<__attribute__((address_space(3))) unsigned int*>(
        reinterpret_cast<uintptr_t>(lp));
    __builtin_amdgcn_global_load_lds(g, l, 16, 0, 0);
}

// ---------------- small utility kernels ----------------

__global__ void zero_kernel(float4* p, int n4) {
    int i = blockIdx.x * 256 + threadIdx.x;
    if (i < n4) p[i] = make_float4(0.f, 0.f, 0.f, 0.f);
}

__global__ void init_kernel(int* counts, int* cursor) {
    if (threadIdx.x < N_EXP) { counts[threadIdx.x] = 0; cursor[threadIdx.x] = 0; }
}

// ---------------- router: fp32 logits, top-2, softmax gates ----------------
// one wave per token
__global__ void router_kernel(const float* __restrict__ x, const float* __restrict__ rw,
                              float* __restrict__ logits, int* __restrict__ tok_expert,
                              float* __restrict__ tok_gate, int* __restrict__ counts) {
    int t = blockIdx.x;
    int lane = threadIdx.x;               // blockDim = 64
    const float* xr = x + (size_t)t * DMODEL;
    float acc[N_EXP];
#pragma unroll
    for (int e = 0; e < N_EXP; ++e) acc[e] = 0.f;
    for (int i = 0; i < DMODEL / 64; ++i) {
        int k = lane + i * 64;
        float xv = xr[k];
#pragma unroll
        for (int e = 0; e < N_EXP; ++e) acc[e] += xv * rw[e * DMODEL + k];
    }
#pragma unroll
    for (int e = 0; e < N_EXP; ++e) {
        float v = acc[e];
        for (int off = 32; off > 0; off >>= 1) v += __shfl_down(v, off, 64);
        acc[e] = v;
    }
    if (lane == 0) {
        float* lg = logits + (size_t)t * N_EXP;
#pragma unroll
        for (int e = 0; e < N_EXP; ++e) lg[e] = acc[e];
        // top-2, ties -> lowest index (matches jax.lax.top_k)
        int e0 = 0; float v0 = acc[0];
#pragma unroll
        for (int e = 1; e < N_EXP; ++e) if (acc[e] > v0) { v0 = acc[e]; e0 = e; }
        int e1 = -1; float v1 = -3.0e38f;
#pragma unroll
        for (int e = 0; e < N_EXP; ++e) if (e != e0 && acc[e] > v1) { v1 = acc[e]; e1 = e; }
        float ex = expf(v1 - v0);
        float g0 = 1.0f / (1.0f + ex);
        float g1 = ex / (1.0f + ex);
        tok_expert[t * 2 + 0] = e0;  tok_gate[t * 2 + 0] = g0;
        tok_expert[t * 2 + 1] = e1;  tok_gate[t * 2 + 1] = g1;
        atomicAdd(&counts[e0], 1);
        atomicAdd(&counts[e1], 1);
    }
}

__global__ void scan_kernel(const int* __restrict__ counts, int* __restrict__ offs) {
    if (threadIdx.x == 0) {
        int s = 0;
        for (int e = 0; e < N_EXP; ++e) { offs[e] = s; s += counts[e]; }
    }
}

// ---------------- gather: compact slot rows, x -> bf16 ----------------
// one block per slot (8192 blocks x 256 threads)
__global__ void gather_kernel(const float* __restrict__ x, const int* __restrict__ tok_expert,
                              const float* __restrict__ tok_gate, const int* __restrict__ offs,
                              int* __restrict__ cursor, u16* __restrict__ Abf,
                              int* __restrict__ perm, float* __restrict__ rowgate) {
    int j = blockIdx.x;                   // slot = token*2 + s
    __shared__ int srow;
    if (threadIdx.x == 0) {
        int e = tok_expert[j];
        int pos = atomicAdd(&cursor[e], 1);
        int row = offs[e] + pos;
        perm[row] = j;
        rowgate[row] = tok_gate[j];
        srow = row;
    }
    __syncthreads();
    int row = srow;
    int t = j >> 1;
    float4 v = ((const float4*)(x + (size_t)t * DMODEL))[threadIdx.x];
    u16x4 o = { f2bf(v.x), f2bf(v.y), f2bf(v.z), f2bf(v.w) };
    *(u16x4*)(Abf + (size_t)row * DMODEL + threadIdx.x * 4) = o;
}

// ---------------- GEMM1: act = silu(A @ Win1^T) * (A @ Win2^T), bf16 MFMA ----------------
// tile: BM=128 rows x BN=64 act-cols, BK=32. Each block also stages w_in rows n+2048 (h2 half).
__global__ __launch_bounds__(256, 2)
void gemm1_kernel(const u16* __restrict__ Abf, const float* __restrict__ win,
                  u16* __restrict__ act, const int* __restrict__ offs,
                  const int* __restrict__ counts) {
    int e = blockIdx.z;
    int cnt = counts[e];
    int mt = blockIdx.y;
    if (mt * 128 >= cnt) return;
    int row0 = offs[e] + mt * 128;
    int n0 = blockIdx.x * 64;
    const float* wb = win + (size_t)e * (2 * DFF) * DMODEL;

    __shared__ u16 lsA[128 * 32];
    __shared__ u16 lsB[2][64 * 32];

    int tid = threadIdx.x, lane = tid & 63, wave = tid >> 6;
    int wm = wave >> 1, wn = wave & 1;

    f32x4 acc[2][4][2];
    f32x4 zero = {0.f, 0.f, 0.f, 0.f};
#pragma unroll
    for (int h = 0; h < 2; ++h)
#pragma unroll
        for (int mi = 0; mi < 4; ++mi)
#pragma unroll
            for (int ni = 0; ni < 2; ++ni) acc[h][mi][ni] = zero;

    int a_rl = wave * 32 + (lane >> 2);   // local row for A staging
    int a_cb = (lane & 3) * 8;            // element offset (8 bf16 = 16B)
    int b_r = tid >> 2;                   // 0..63
    int b_c = (tid & 3) * 8;              // 0..24

    for (int kk = 0; kk < DMODEL / 32; ++kk) {
        int k0 = kk * 32;
        // A tile: 128x32 bf16 via async direct-to-LDS (2 issues/wave, 16 rows each)
        {
            const u16* g0 = Abf + (size_t)(row0 + a_rl) * DMODEL + k0 + a_cb;
            g2l16(g0, &lsA[(wave * 32) * 32]);
            g2l16(g0 + 16 * DMODEL, &lsA[(wave * 32 + 16) * 32]);
        }
        // B tiles (h1 rows n0.., h2 rows n0+2048..): fp32 load -> bf16 -> LDS
#pragma unroll
        for (int h = 0; h < 2; ++h) {
            const float* g = wb + (size_t)(n0 + h * DFF + b_r) * DMODEL + k0 + b_c;
            float4 v0 = *(const float4*)g;
            float4 v1 = *(const float4*)(g + 4);
            u16x8 o = { f2bf(v0.x), f2bf(v0.y), f2bf(v0.z), f2bf(v0.w),
                        f2bf(v1.x), f2bf(v1.y), f2bf(v1.z), f2bf(v1.w) };
            *(u16x8*)&lsB[h][b_r * 32 + b_c] = o;
        }
        __syncthreads();
        bf16x8 afr[4];
#pragma unroll
        for (int mi = 0; mi < 4; ++mi) {
            int ar = wm * 64 + mi * 16 + (lane & 15);
            afr[mi] = *(const bf16x8*)&lsA[ar * 32 + (lane >> 4) * 8];
        }
#pragma unroll
        for (int h = 0; h < 2; ++h)
#pragma unroll
            for (int ni = 0; ni < 2; ++ni) {
                int br = wn * 32 + ni * 16 + (lane & 15);
                bf16x8 bfr = *(const bf16x8*)&lsB[h][br * 32 + (lane >> 4) * 8];
#pragma unroll
                for (int mi = 0; mi < 4; ++mi)
                    acc[h][mi][ni] = __builtin_amdgcn_mfma_f32_16x16x32_bf16(
                        afr[mi], bfr, acc[h][mi][ni], 0, 0, 0);
            }
        __syncthreads();
    }
    // epilogue: act = silu(h1) * h2, store bf16
    int mmax = cnt - mt * 128;
#pragma unroll
    for (int mi = 0; mi < 4; ++mi)
#pragma unroll
        for (int i = 0; i < 4; ++i) {
            int rl = wm * 64 + mi * 16 + (lane >> 4) * 4 + i;
            if (rl < mmax) {
                size_t rp = (size_t)(row0 + rl) * DFF;
#pragma unroll
                for (int ni = 0; ni < 2; ++ni) {
                    int col = n0 + wn * 32 + ni * 16 + (lane & 15);
                    float a = acc[0][mi][ni][i];
                    float b = acc[1][mi][ni][i];
                    float s = a / (1.0f + __expf(-a));
                    act[rp + col] = f2bf(s * b);
                }
            }
        }
}

// ---------------- GEMM2: y = act @ Wout^T, scaled atomic scatter into out ----------------
// tile: BM=128 x BN=128, BK=32, K=2048
__global__ __launch_bounds__(256, 2)
void gemm2_kernel(const u16* __restrict__ act, const float* __restrict__ wout,
                  float* __restrict__ out, const int* __restrict__ offs,
                  const int* __restrict__ counts, const int* __restrict__ perm,
                  const float* __restrict__ rowgate) {
    int e = blockIdx.z;
    int cnt = counts[e];
    int mt = blockIdx.y;
    if (mt * 128 >= cnt) return;
    int row0 = offs[e] + mt * 128;
    int n0 = blockIdx.x * 128;
    const float* wb = wout + (size_t)e * DMODEL * DFF;

    __shared__ u16 lsA[128 * 32];
    __shared__ u16 lsB[128 * 32];

    int tid = threadIdx.x, lane = tid & 63, wave = tid >> 6;
    int wm = wave >> 1, wn = wave & 1;

    f32x4 acc[4][4];
    f32x4 zero = {0.f, 0.f, 0.f, 0.f};
#pragma unroll
    for (int mi = 0; mi < 4; ++mi)
#pragma unroll
        for (int ni = 0; ni < 4; ++ni) acc[mi][ni] = zero;

    int a_rl = wave * 32 + (lane >> 2);
    int a_cb = (lane & 3) * 8;
    int b_r = tid >> 1;                   // 0..127
    int b_c = (tid & 1) * 16;             // 0 or 16 floats

    for (int kk = 0; kk < DFF / 32; ++kk) {
        int k0 = kk * 32;
        {
            const u16* g0 = act + (size_t)(row0 + a_rl) * DFF + k0 + a_cb;
            g2l16(g0, &lsA[(wave * 32) * 32]);
            g2l16(g0 + 16 * DFF, &lsA[(wave * 32 + 16) * 32]);
        }
        {
            const float* g = wb + (size_t)(n0 + b_r) * DFF + k0 + b_c;
            float4 v0 = *(const float4*)g;
            float4 v1 = *(const float4*)(g + 4);
            float4 v2 = *(const float4*)(g + 8);
            float4 v3 = *(const float4*)(g + 12);
            u16x8 o0 = { f2bf(v0.x), f2bf(v0.y), f2bf(v0.z), f2bf(v0.w),
                         f2bf(v1.x), f2bf(v1.y), f2bf(v1.z), f2bf(v1.w) };
            u16x8 o1 = { f2bf(v2.x), f2bf(v2.y), f2bf(v2.z), f2bf(v2.w),
                         f2bf(v3.x), f2bf(v3.y), f2bf(v3.z), f2bf(v3.w) };
            *(u16x8*)&lsB[b_r * 32 + b_c] = o0;
            *(u16x8*)&lsB[b_r * 32 + b_c + 8] = o1;
        }
        __syncthreads();
        bf16x8 afr[4];
#pragma unroll
        for (int mi = 0; mi < 4; ++mi) {
            int ar = wm * 64 + mi * 16 + (lane & 15);
            afr[mi] = *(const bf16x8*)&lsA[ar * 32 + (lane >> 4) * 8];
        }
#pragma unroll
        for (int ni = 0; ni < 4; ++ni) {
            int br = wn * 64 + ni * 16 + (lane & 15);
            bf16x8 bfr = *(const bf16x8*)&lsB[br * 32 + (lane >> 4) * 8];
#pragma unroll
            for (int mi = 0; mi < 4; ++mi)
                acc[mi][ni] = __builtin_amdgcn_mfma_f32_16x16x32_bf16(
                    afr[mi], bfr, acc[mi][ni], 0, 0, 0);
        }
        __syncthreads();
    }
    // epilogue: out[token] += gate * y   (2 non-conflicting adds per out element)
    int mmax = cnt - mt * 128;
#pragma unroll
    for (int mi = 0; mi < 4; ++mi)
#pragma unroll
        for (int i = 0; i < 4; ++i) {
            int rl = wm * 64 + mi * 16 + (lane >> 4) * 4 + i;
            if (rl < mmax) {
                int gr = row0 + rl;
                int j = perm[gr];
                int t = j >> 1;
                float gate = rowgate[gr];
                float* orow = out + (size_t)t * DMODEL;
#pragma unroll
                for (int ni = 0; ni < 4; ++ni) {
                    int col = n0 + wn * 64 + ni * 16 + (lane & 15);
                    atomicAdd(&orow[col], gate * acc[mi][ni][i]);
                }
            }
        }
}

// ---------------- launch ----------------
extern "C" void kernel_launch(void* const* d_in, const int* in_sizes, int n_in,
                              void* d_out, int out_size, void* d_ws, size_t ws_size,
                              hipStream_t stream) {
    const float* x    = (const float*)d_in[0];   // [4096, 1024]
    const float* rw   = (const float*)d_in[1];   // [8, 1024]
    const float* win  = (const float*)d_in[2];   // [8, 4096, 1024]
    const float* wout = (const float*)d_in[3];   // [8, 1024, 2048]
    float* out    = (float*)d_out;               // [4096, 1024]
    float* logits = out + (size_t)N_TOK * DMODEL; // [4096, 8]

    char* ws = (char*)d_ws;
    size_t o = 0;
    auto alloc = [&](size_t bytes) -> void* {
        void* p = ws + o;
        o = (o + bytes + 255) & ~(size_t)255;
        return p;
    };
    u16*   Abf      = (u16*)  alloc((size_t)ROWS_PAD * DMODEL * 2);  // 17.0 MB
    u16*   actbuf   = (u16*)  alloc((size_t)ROWS_PAD * DFF * 2);     // 34.1 MB
    int*   counts   = (int*)  alloc(N_EXP * 4);
    int*   cursor   = (int*)  alloc(N_EXP * 4);
    int*   offs     = (int*)  alloc(16 * 4);
    int*   perm     = (int*)  alloc(ROWS_PAD * 4);
    float* rowgate  = (float*)alloc(ROWS_PAD * 4);
    int*   tok_exp  = (int*)  alloc(N_SLOTS * 4);
    float* tok_gate = (float*)alloc(N_SLOTS * 4);
    (void)ws_size; (void)in_sizes; (void)n_in; (void)out_size;

    // zero the full output (out region accumulated by atomics; logits overwritten)
    zero_kernel<<<4128, 256, 0, stream>>>((float4*)out, (N_TOK * DMODEL + N_TOK * N_EXP) / 4);
    init_kernel<<<1, 64, 0, stream>>>(counts, cursor);
    router_kernel<<<N_TOK, 64, 0, stream>>>(x, rw, logits, tok_exp, tok_gate, counts);
    scan_kernel<<<1, 64, 0, stream>>>(counts, offs);
    gather_kernel<<<N_SLOTS, 256, 0, stream>>>(x, tok_exp, tok_gate, offs, cursor,
                                               Abf, perm, rowgate);
    gemm1_kernel<<<dim3(DFF / 64, 32, N_EXP), 256, 0, stream>>>(Abf, win, actbuf, offs, counts);
    gemm2_kernel<<<dim3(DMODEL / 128, 32, N_EXP), 256, 0, stream>>>(actbuf, wout, out, offs,
                                                                    counts, perm, rowgate);
}

// Round 2
// 654.626 us; speedup vs baseline: 1.0404x; 1.0404x over previous
//
#include <hip/hip_runtime.h>
#include <stdint.h>

#define N_TOK   4096
#define DMODEL  1024
#define DFF     2048
#define N_EXP   8
#define N_SLOTS (N_TOK * 2)        // 8192 (every token has exactly 2 expert slots)
#define ROWS_PAD (N_SLOTS + 128)   // padding so tile-tail OOB reads stay in-bounds

typedef __bf16 bf16x8 __attribute__((ext_vector_type(8)));
typedef float  f32x4  __attribute__((ext_vector_type(4)));
typedef unsigned short u16;
typedef unsigned short u16x8 __attribute__((ext_vector_type(8)));
typedef unsigned short u16x4 __attribute__((ext_vector_type(4)));

__device__ __forceinline__ u16 f2bf(float f) {
    union { float f; uint32_t u; } v; v.f = f;
    uint32_t r = v.u + 0x7FFFu + ((v.u >> 16) & 1u);  // RTNE
    return (u16)(r >> 16);
}

// async 16B/lane global->LDS. LDS dest is wave-uniform base + lane*16 (m104 caveat).
__device__ __forceinline__ void g2l16(const void* gp, void* lp) {
    auto g = reinterpret_cast<const __attribute__((address_space(1))) unsigned int*>(
        reinterpret_cast<uintptr_t>(gp));
    auto l = reinterpret_cast<__attribute__((address_space(3))) unsigned int*>(
        reinterpret_cast<uintptr_t>(lp));
    __builtin_amdgcn_global_load_lds(g, l, 16, 0, 0);
}

// ---------------- small utility kernels ----------------

__global__ void zero_kernel(float4* p, int n4) {
    int i = blockIdx.x * 256 + threadIdx.x;
    if (i < n4) p[i] = make_float4(0.f, 0.f, 0.f, 0.f);
}

__global__ void init_kernel(int* counts, int* cursor) {
    if (threadIdx.x < N_EXP) { counts[threadIdx.x] = 0; cursor[threadIdx.x] = 0; }
}

// fp32 -> bf16 weight conversion (exact element counts, no bounds check needed)
__global__ void cvt_kernel(const float4* __restrict__ src, u16x8* __restrict__ dst) {
    int i = blockIdx.x * 256 + threadIdx.x;
    float4 a = src[i * 2];
    float4 b = src[i * 2 + 1];
    u16x8 o = { f2bf(a.x), f2bf(a.y), f2bf(a.z), f2bf(a.w),
                f2bf(b.x), f2bf(b.y), f2bf(b.z), f2bf(b.w) };
    dst[i] = o;
}

// ---------------- router: fp32 logits, top-2, softmax gates ----------------
// one wave per token
__global__ void router_kernel(const float* __restrict__ x, const float* __restrict__ rw,
                              float* __restrict__ logits, int* __restrict__ tok_expert,
                              float* __restrict__ tok_gate, int* __restrict__ counts) {
    int t = blockIdx.x;
    int lane = threadIdx.x;               // blockDim = 64
    const float* xr = x + (size_t)t * DMODEL;
    float acc[N_EXP];
#pragma unroll
    for (int e = 0; e < N_EXP; ++e) acc[e] = 0.f;
    for (int i = 0; i < DMODEL / 64; ++i) {
        int k = lane + i * 64;
        float xv = xr[k];
#pragma unroll
        for (int e = 0; e < N_EXP; ++e) acc[e] += xv * rw[e * DMODEL + k];
    }
#pragma unroll
    for (int e = 0; e < N_EXP; ++e) {
        float v = acc[e];
        for (int off = 32; off > 0; off >>= 1) v += __shfl_down(v, off, 64);
        acc[e] = v;
    }
    if (lane == 0) {
        float* lg = logits + (size_t)t * N_EXP;
#pragma unroll
        for (int e = 0; e < N_EXP; ++e) lg[e] = acc[e];
        // top-2, ties -> lowest index (matches jax.lax.top_k)
        int e0 = 0; float v0 = acc[0];
#pragma unroll
        for (int e = 1; e < N_EXP; ++e) if (acc[e] > v0) { v0 = acc[e]; e0 = e; }
        int e1 = -1; float v1 = -3.0e38f;
#pragma unroll
        for (int e = 0; e < N_EXP; ++e) if (e != e0 && acc[e] > v1) { v1 = acc[e]; e1 = e; }
        float ex = expf(v1 - v0);
        float g0 = 1.0f / (1.0f + ex);
        float g1 = ex / (1.0f + ex);
        tok_expert[t * 2 + 0] = e0;  tok_gate[t * 2 + 0] = g0;
        tok_expert[t * 2 + 1] = e1;  tok_gate[t * 2 + 1] = g1;
        atomicAdd(&counts[e0], 1);
        atomicAdd(&counts[e1], 1);
    }
}

__global__ void scan_kernel(const int* __restrict__ counts, int* __restrict__ offs) {
    if (threadIdx.x == 0) {
        int s = 0;
        for (int e = 0; e < N_EXP; ++e) { offs[e] = s; s += counts[e]; }
    }
}

// ---------------- gather: compact slot rows, x -> bf16 ----------------
// one block per slot (8192 blocks x 256 threads)
__global__ void gather_kernel(const float* __restrict__ x, const int* __restrict__ tok_expert,
                              const float* __restrict__ tok_gate, const int* __restrict__ offs,
                              int* __restrict__ cursor, u16* __restrict__ Abf,
                              int* __restrict__ perm, float* __restrict__ rowgate) {
    int j = blockIdx.x;                   // slot = token*2 + s
    __shared__ int srow;
    if (threadIdx.x == 0) {
        int e = tok_expert[j];
        int pos = atomicAdd(&cursor[e], 1);
        int row = offs[e] + pos;
        perm[row] = j;
        rowgate[row] = tok_gate[j];
        srow = row;
    }
    __syncthreads();
    int row = srow;
    int t = j >> 1;
    float4 v = ((const float4*)(x + (size_t)t * DMODEL))[threadIdx.x];
    u16x4 o = { f2bf(v.x), f2bf(v.y), f2bf(v.z), f2bf(v.w) };
    *(u16x4*)(Abf + (size_t)row * DMODEL + threadIdx.x * 4) = o;
}

// ---------------- GEMM1: act = silu(A @ Win1^T) * (A @ Win2^T), bf16 MFMA ----------------
// tile: BM=128 rows x BN=64 act-cols (x2 SwiGLU halves), BK=32, all-async staging.
__global__ __launch_bounds__(256, 2)
void gemm1_kernel(const u16* __restrict__ Abf, const u16* __restrict__ winbf,
                  u16* __restrict__ act, const int* __restrict__ offs,
                  const int* __restrict__ counts) {
    int e = blockIdx.z;
    int cnt = counts[e];
    int mt = blockIdx.y;
    if (mt * 128 >= cnt) return;
    int row0 = offs[e] + mt * 128;
    int n0 = blockIdx.x * 64;
    const u16* wb = winbf + (size_t)e * (2 * DFF) * DMODEL;

    __shared__ u16 lsA[128 * 32];
    __shared__ u16 lsB[2][64 * 32];

    int tid = threadIdx.x, lane = tid & 63, wave = tid >> 6;
    int wm = wave >> 1, wn = wave & 1;

    f32x4 acc[2][4][2];
    f32x4 zero = {0.f, 0.f, 0.f, 0.f};
#pragma unroll
    for (int h = 0; h < 2; ++h)
#pragma unroll
        for (int mi = 0; mi < 4; ++mi)
#pragma unroll
            for (int ni = 0; ni < 2; ++ni) acc[h][mi][ni] = zero;

    int s_row = lane >> 2;                // 0..15
    int s_col = (lane & 3) * 8;           // element offset (8 bf16 = 16B)

    for (int kk = 0; kk < DMODEL / 32; ++kk) {
        int k0 = kk * 32;
        // A tile: 128x32 bf16, 2 async issues/wave (16 rows each)
        const u16* ga = Abf + (size_t)(row0 + wave * 32 + s_row) * DMODEL + k0 + s_col;
        g2l16(ga, &lsA[(wave * 32) * 32]);
        g2l16(ga + 16 * DMODEL, &lsA[(wave * 32 + 16) * 32]);
        // B tiles (h1 rows n0.., h2 rows n0+DFF..): 1 async issue/wave per half
        const u16* gb0 = wb + (size_t)(n0 + wave * 16 + s_row) * DMODEL + k0 + s_col;
        g2l16(gb0, &lsB[0][(wave * 16) * 32]);
        g2l16(gb0 + (size_t)DFF * DMODEL, &lsB[1][(wave * 16) * 32]);
        __syncthreads();
        bf16x8 afr[4];
#pragma unroll
        for (int mi = 0; mi < 4; ++mi) {
            int ar = wm * 64 + mi * 16 + (lane & 15);
            afr[mi] = *(const bf16x8*)&lsA[ar * 32 + (lane >> 4) * 8];
        }
#pragma unroll
        for (int h = 0; h < 2; ++h)
#pragma unroll
            for (int ni = 0; ni < 2; ++ni) {
                int br = wn * 32 + ni * 16 + (lane & 15);
                bf16x8 bfr = *(const bf16x8*)&lsB[h][br * 32 + (lane >> 4) * 8];
#pragma unroll
                for (int mi = 0; mi < 4; ++mi)
                    acc[h][mi][ni] = __builtin_amdgcn_mfma_f32_16x16x32_bf16(
                        afr[mi], bfr, acc[h][mi][ni], 0, 0, 0);
            }
        __syncthreads();
    }
    // epilogue: act = silu(h1) * h2, store bf16
    int mmax = cnt - mt * 128;
#pragma unroll
    for (int mi = 0; mi < 4; ++mi)
#pragma unroll
        for (int i = 0; i < 4; ++i) {
            int rl = wm * 64 + mi * 16 + (lane >> 4) * 4 + i;
            if (rl < mmax) {
                size_t rp = (size_t)(row0 + rl) * DFF;
#pragma unroll
                for (int ni = 0; ni < 2; ++ni) {
                    int col = n0 + wn * 32 + ni * 16 + (lane & 15);
                    float a = acc[0][mi][ni][i];
                    float b = acc[1][mi][ni][i];
                    float s = a / (1.0f + __expf(-a));
                    act[rp + col] = f2bf(s * b);
                }
            }
        }
}

// ---------------- GEMM2: y = act @ Wout^T, split-K=2, scaled atomic scatter ----------------
// tile: BM=128 x BN=128, BK=32, K=1024 per block
__global__ __launch_bounds__(256, 2)
void gemm2_kernel(const u16* __restrict__ act, const u16* __restrict__ woutbf,
                  float* __restrict__ out, const int* __restrict__ offs,
                  const int* __restrict__ counts, const int* __restrict__ perm,
                  const float* __restrict__ rowgate) {
    int e = blockIdx.z >> 1;
    int kc = blockIdx.z & 1;
    int cnt = counts[e];
    int mt = blockIdx.y;
    if (mt * 128 >= cnt) return;
    int row0 = offs[e] + mt * 128;
    int n0 = blockIdx.x * 128;
    const u16* wb = woutbf + (size_t)e * DMODEL * DFF;

    __shared__ u16 lsA[128 * 32];
    __shared__ u16 lsB[128 * 32];

    int tid = threadIdx.x, lane = tid & 63, wave = tid >> 6;
    int wm = wave >> 1, wn = wave & 1;

    f32x4 acc[4][4];
    f32x4 zero = {0.f, 0.f, 0.f, 0.f};
#pragma unroll
    for (int mi = 0; mi < 4; ++mi)
#pragma unroll
        for (int ni = 0; ni < 4; ++ni) acc[mi][ni] = zero;

    int s_row = lane >> 2;
    int s_col = (lane & 3) * 8;

    for (int kk = kc * 32; kk < kc * 32 + 32; ++kk) {
        int k0 = kk * 32;
        const u16* ga = act + (size_t)(row0 + wave * 32 + s_row) * DFF + k0 + s_col;
        g2l16(ga, &lsA[(wave * 32) * 32]);
        g2l16(ga + 16 * DFF, &lsA[(wave * 32 + 16) * 32]);
        const u16* gb = wb + (size_t)(n0 + wave * 32 + s_row) * DFF + k0 + s_col;
        g2l16(gb, &lsB[(wave * 32) * 32]);
        g2l16(gb + 16 * DFF, &lsB[(wave * 32 + 16) * 32]);
        __syncthreads();
        bf16x8 afr[4];
#pragma unroll
        for (int mi = 0; mi < 4; ++mi) {
            int ar = wm * 64 + mi * 16 + (lane & 15);
            afr[mi] = *(const bf16x8*)&lsA[ar * 32 + (lane >> 4) * 8];
        }
#pragma unroll
        for (int ni = 0; ni < 4; ++ni) {
            int br = wn * 64 + ni * 16 + (lane & 15);
            bf16x8 bfr = *(const bf16x8*)&lsB[br * 32 + (lane >> 4) * 8];
#pragma unroll
            for (int mi = 0; mi < 4; ++mi)
                acc[mi][ni] = __builtin_amdgcn_mfma_f32_16x16x32_bf16(
                    afr[mi], bfr, acc[mi][ni], 0, 0, 0);
        }
        __syncthreads();
    }
    // epilogue: out[token] += gate * y  (4 non-conflicting adds per out element w/ split-K=2)
    int mmax = cnt - mt * 128;
#pragma unroll
    for (int mi = 0; mi < 4; ++mi)
#pragma unroll
        for (int i = 0; i < 4; ++i) {
            int rl = wm * 64 + mi * 16 + (lane >> 4) * 4 + i;
            if (rl < mmax) {
                int gr = row0 + rl;
                int j = perm[gr];
                int t = j >> 1;
                float gate = rowgate[gr];
                float* orow = out + (size_t)t * DMODEL;
#pragma unroll
                for (int ni = 0; ni < 4; ++ni) {
                    int col = n0 + wn * 64 + ni * 16 + (lane & 15);
                    atomicAdd(&orow[col], gate * acc[mi][ni][i]);
                }
            }
        }
}

// ---------------- launch ----------------
extern "C" void kernel_launch(void* const* d_in, const int* in_sizes, int n_in,
                              void* d_out, int out_size, void* d_ws, size_t ws_size,
                              hipStream_t stream) {
    const float* x    = (const float*)d_in[0];   // [4096, 1024]
    const float* rw   = (const float*)d_in[1];   // [8, 1024]
    const float* win  = (const float*)d_in[2];   // [8, 4096, 1024]
    const float* wout = (const float*)d_in[3];   // [8, 1024, 2048]
    float* out    = (float*)d_out;               // [4096, 1024]
    float* logits = out + (size_t)N_TOK * DMODEL; // [4096, 8]

    char* ws = (char*)d_ws;
    size_t o = 0;
    auto alloc = [&](size_t bytes) -> void* {
        void* p = ws + o;
        o = (o + bytes + 255) & ~(size_t)255;
        return p;
    };
    u16*   Abf      = (u16*)  alloc((size_t)ROWS_PAD * DMODEL * 2);       // 17.0 MB
    u16*   actbuf   = (u16*)  alloc((size_t)ROWS_PAD * DFF * 2);          // 34.1 MB
    u16*   winbf    = (u16*)  alloc((size_t)N_EXP * 2 * DFF * DMODEL * 2); // 67.1 MB
    u16*   woutbf   = (u16*)  alloc((size_t)N_EXP * DMODEL * DFF * 2);    // 33.6 MB
    int*   counts   = (int*)  alloc(N_EXP * 4);
    int*   cursor   = (int*)  alloc(N_EXP * 4);
    int*   offs     = (int*)  alloc(16 * 4);
    int*   perm     = (int*)  alloc(ROWS_PAD * 4);
    float* rowgate  = (float*)alloc(ROWS_PAD * 4);
    int*   tok_exp  = (int*)  alloc(N_SLOTS * 4);
    float* tok_gate = (float*)alloc(N_SLOTS * 4);
    (void)ws_size; (void)in_sizes; (void)n_in; (void)out_size;

    // zero the full output (out region accumulated by atomics; logits overwritten)
    zero_kernel<<<4128, 256, 0, stream>>>((float4*)out, (N_TOK * DMODEL + N_TOK * N_EXP) / 4);
    init_kernel<<<1, 64, 0, stream>>>(counts, cursor);
    // weight fp32->bf16 pre-conversion (removes in-loop VALU staging from both GEMMs)
    cvt_kernel<<<(N_EXP * 2 * DFF * DMODEL / 8) / 256, 256, 0, stream>>>(
        (const float4*)win, (u16x8*)winbf);
    cvt_kernel<<<(N_EXP * DMODEL * DFF / 8) / 256, 256, 0, stream>>>(
        (const float4*)wout, (u16x8*)woutbf);
    router_kernel<<<N_TOK, 64, 0, stream>>>(x, rw, logits, tok_exp, tok_gate, counts);
    scan_kernel<<<1, 64, 0, stream>>>(counts, offs);
    gather_kernel<<<N_SLOTS, 256, 0, stream>>>(x, tok_exp, tok_gate, offs, cursor,
                                               Abf, perm, rowgate);
    gemm1_kernel<<<dim3(DFF / 64, 32, N_EXP), 256, 0, stream>>>(Abf, winbf, actbuf, offs, counts);
    gemm2_kernel<<<dim3(DMODEL / 128, 32, N_EXP * 2), 256, 0, stream>>>(actbuf, woutbf, out, offs,
                                                                        counts, perm, rowgate);
}

// Round 3
// 557.509 us; speedup vs baseline: 1.2217x; 1.1742x over previous
//
#include <hip/hip_runtime.h>
#include <stdint.h>

#define N_TOK   4096
#define DMODEL  1024
#define DFF     2048
#define N_EXP   8
#define N_SLOTS (N_TOK * 2)        // 8192 (every token has exactly 2 expert slots)
#define ROWS_PAD (N_SLOTS + 128)   // padding so tile-tail OOB reads stay in-bounds
#define MT_MAX  16                 // m-tiles per expert (16*128=2048 rows; E[cnt]=1024)

typedef __bf16 bf16x8 __attribute__((ext_vector_type(8)));
typedef float  f32x4  __attribute__((ext_vector_type(4)));
typedef unsigned short u16;
typedef unsigned short u16x8 __attribute__((ext_vector_type(8)));
typedef unsigned short u16x4 __attribute__((ext_vector_type(4)));

__device__ __forceinline__ u16 f2bf(float f) {
    union { float f; uint32_t u; } v; v.f = f;
    uint32_t r = v.u + 0x7FFFu + ((v.u >> 16) & 1u);  // RTNE
    return (u16)(r >> 16);
}
__device__ __forceinline__ float bf2f(u16 u) {
    union { uint32_t u; float f; } v; v.u = ((uint32_t)u) << 16;
    return v.f;
}

// async 16B/lane global->LDS. LDS dest is wave-uniform base + lane*16 (m104 caveat).
__device__ __forceinline__ void g2l16(const void* gp, void* lp) {
    auto g = reinterpret_cast<const __attribute__((address_space(1))) unsigned int*>(
        reinterpret_cast<uintptr_t>(gp));
    auto l = reinterpret_cast<__attribute__((address_space(3))) unsigned int*>(
        reinterpret_cast<uintptr_t>(lp));
    __builtin_amdgcn_global_load_lds(g, l, 16, 0, 0);
}

// ---- XOR bank-swizzle for 32-u16-wide LDS tiles (row stride 64B = 16 banks) ----
// slot(r,cb) = cb ^ (r&3) ^ ((r>>2)&1): makes 16-lane frag-read phases 2-way max (free).
// Loader lane l (16-row chunk, row = R0+(l>>2), R0%16==0) must fetch global col-block:
__device__ __forceinline__ int src_cb(int l) {
    return (l & 3) ^ ((l >> 2) & 3) ^ ((l >> 4) & 1);
}
// LDS u16 index of (tile-row r, col-block cb):
__device__ __forceinline__ int lds_idx(int r, int cb) {
    int s = cb ^ (r & 3) ^ ((r >> 2) & 1);
    return r * 32 + s * 8;
}

// ---------------- merged fp32 -> bf16 weight conversion (one dispatch) ----------------
#define WIN_V8  (N_EXP * 2 * DFF * DMODEL / 8)   // 4194304
#define WOUT_V8 (N_EXP * DMODEL * DFF / 8)       // 2097152
__global__ void cvt_kernel(const float4* __restrict__ win, const float4* __restrict__ wout,
                           u16x8* __restrict__ winbf, u16x8* __restrict__ woutbf) {
    int i = blockIdx.x * 256 + threadIdx.x;
    const float4* s; u16x8* d; int k;
    if (i < WIN_V8) { s = win;  d = winbf;  k = i; }
    else            { s = wout; d = woutbf; k = i - WIN_V8; }
    float4 a = s[k * 2];
    float4 b = s[k * 2 + 1];
    u16x8 o = { f2bf(a.x), f2bf(a.y), f2bf(a.z), f2bf(a.w),
                f2bf(b.x), f2bf(b.y), f2bf(b.z), f2bf(b.w) };
    d[k] = o;
}

// ---------------- router: fp32 logits, top-2, softmax gates ----------------
// one wave per token
__global__ void router_kernel(const float* __restrict__ x, const float* __restrict__ rw,
                              float* __restrict__ logits, int* __restrict__ tok_expert,
                              float* __restrict__ tok_gate) {
    int t = blockIdx.x;
    int lane = threadIdx.x;               // blockDim = 64
    const float* xr = x + (size_t)t * DMODEL;
    float acc[N_EXP];
#pragma unroll
    for (int e = 0; e < N_EXP; ++e) acc[e] = 0.f;
    for (int i = 0; i < DMODEL / 64; ++i) {
        int k = lane + i * 64;
        float xv = xr[k];
#pragma unroll
        for (int e = 0; e < N_EXP; ++e) acc[e] += xv * rw[e * DMODEL + k];
    }
#pragma unroll
    for (int e = 0; e < N_EXP; ++e) {
        float v = acc[e];
        for (int off = 32; off > 0; off >>= 1) v += __shfl_down(v, off, 64);
        acc[e] = v;
    }
    if (lane == 0) {
        float* lg = logits + (size_t)t * N_EXP;
#pragma unroll
        for (int e = 0; e < N_EXP; ++e) lg[e] = acc[e];
        // top-2, ties -> lowest index (matches jax.lax.top_k)
        int e0 = 0; float v0 = acc[0];
#pragma unroll
        for (int e = 1; e < N_EXP; ++e) if (acc[e] > v0) { v0 = acc[e]; e0 = e; }
        int e1 = -1; float v1 = -3.0e38f;
#pragma unroll
        for (int e = 0; e < N_EXP; ++e) if (e != e0 && acc[e] > v1) { v1 = acc[e]; e1 = e; }
        float ex = expf(v1 - v0);
        tok_expert[t * 2 + 0] = e0;  tok_gate[t * 2 + 0] = 1.0f / (1.0f + ex);
        tok_expert[t * 2 + 1] = e1;  tok_gate[t * 2 + 1] = ex / (1.0f + ex);
    }
}

// ---------------- scan: count experts, prefix-sum offs, zero cursor ----------------
__global__ void scan_kernel(const int* __restrict__ tok_expert, int* __restrict__ offs,
                            int* __restrict__ cursor) {
    __shared__ int cnt[N_EXP];
    int tid = threadIdx.x;                // 256
    if (tid < N_EXP) { cnt[tid] = 0; cursor[tid] = 0; }
    __syncthreads();
    int loc[N_EXP];
#pragma unroll
    for (int e = 0; e < N_EXP; ++e) loc[e] = 0;
    for (int j = tid; j < N_SLOTS; j += 256) {
        int ex = tok_expert[j];
#pragma unroll
        for (int e = 0; e < N_EXP; ++e) loc[e] += (ex == e);
    }
#pragma unroll
    for (int e = 0; e < N_EXP; ++e) if (loc[e]) atomicAdd(&cnt[e], loc[e]);
    __syncthreads();
    if (tid == 0) {
        int s = 0;
        for (int e = 0; e < N_EXP; ++e) { offs[e] = s; s += cnt[e]; }
        offs[N_EXP] = s;
    }
}

// ---------------- gather: compact slot rows, x -> bf16, record slot->row ----------------
__global__ void gather_kernel(const float* __restrict__ x, const int* __restrict__ tok_expert,
                              const int* __restrict__ offs, int* __restrict__ cursor,
                              u16* __restrict__ Abf, int* __restrict__ inv) {
    int j = blockIdx.x;                   // slot = token*2 + s
    __shared__ int srow;
    if (threadIdx.x == 0) {
        int e = tok_expert[j];
        int pos = atomicAdd(&cursor[e], 1);
        int row = offs[e] + pos;
        inv[j] = row;
        srow = row;
    }
    __syncthreads();
    int row = srow;
    int t = j >> 1;
    float4 v = ((const float4*)(x + (size_t)t * DMODEL))[threadIdx.x];
    u16x4 o = { f2bf(v.x), f2bf(v.y), f2bf(v.z), f2bf(v.w) };
    *(u16x4*)(Abf + (size_t)row * DMODEL + threadIdx.x * 4) = o;
}

// ---------------- GEMM1: act = silu(A @ Win1^T) * (A @ Win2^T), bf16 MFMA ----------------
// tile: BM=128 rows x BN=64 act-cols (x2 SwiGLU halves), BK=32, all-async + swizzled LDS.
__global__ __launch_bounds__(256, 2)
void gemm1_kernel(const u16* __restrict__ Abf, const u16* __restrict__ winbf,
                  u16* __restrict__ act, const int* __restrict__ offs) {
    int e = blockIdx.z;
    int cnt = offs[e + 1] - offs[e];
    int mt = blockIdx.y;
    if (mt * 128 >= cnt) return;
    int row0 = offs[e] + mt * 128;
    int n0 = blockIdx.x * 64;
    const u16* wb = winbf + (size_t)e * (2 * DFF) * DMODEL;

    __shared__ u16 lsA[128 * 32];
    __shared__ u16 lsB[2][64 * 32];

    int tid = threadIdx.x, lane = tid & 63, wave = tid >> 6;
    int wm = wave >> 1, wn = wave & 1;

    f32x4 acc[2][4][2];
    f32x4 zero = {0.f, 0.f, 0.f, 0.f};
#pragma unroll
    for (int h = 0; h < 2; ++h)
#pragma unroll
        for (int mi = 0; mi < 4; ++mi)
#pragma unroll
            for (int ni = 0; ni < 2; ++ni) acc[h][mi][ni] = zero;

    int s_row = lane >> 2;                // 0..15 within 16-row chunk
    int s_col = src_cb(lane) * 8;         // swizzled source col-block

    for (int kk = 0; kk < DMODEL / 32; ++kk) {
        int k0 = kk * 32;
        // A tile: 128x32 bf16, 2 async issues/wave (16 rows each)
        const u16* ga = Abf + (size_t)(row0 + wave * 32 + s_row) * DMODEL + k0 + s_col;
        g2l16(ga, &lsA[(wave * 32) * 32]);
        g2l16(ga + 16 * DMODEL, &lsA[(wave * 32 + 16) * 32]);
        // B tiles (h1 rows n0.., h2 rows n0+DFF..): 1 async issue/wave per half
        const u16* gb0 = wb + (size_t)(n0 + wave * 16 + s_row) * DMODEL + k0 + s_col;
        g2l16(gb0, &lsB[0][(wave * 16) * 32]);
        g2l16(gb0 + (size_t)DFF * DMODEL, &lsB[1][(wave * 16) * 32]);
        __syncthreads();
        bf16x8 afr[4];
#pragma unroll
        for (int mi = 0; mi < 4; ++mi)
            afr[mi] = *(const bf16x8*)&lsA[lds_idx(wm * 64 + mi * 16 + (lane & 15), lane >> 4)];
#pragma unroll
        for (int h = 0; h < 2; ++h)
#pragma unroll
            for (int ni = 0; ni < 2; ++ni) {
                bf16x8 bfr = *(const bf16x8*)&lsB[h][lds_idx(wn * 32 + ni * 16 + (lane & 15), lane >> 4)];
#pragma unroll
                for (int mi = 0; mi < 4; ++mi)
                    acc[h][mi][ni] = __builtin_amdgcn_mfma_f32_16x16x32_bf16(
                        afr[mi], bfr, acc[h][mi][ni], 0, 0, 0);
            }
        __syncthreads();
    }
    // epilogue: act = silu(h1) * h2, store bf16
    int mmax = cnt - mt * 128;
#pragma unroll
    for (int mi = 0; mi < 4; ++mi)
#pragma unroll
        for (int i = 0; i < 4; ++i) {
            int rl = wm * 64 + mi * 16 + (lane >> 4) * 4 + i;
            if (rl < mmax) {
                size_t rp = (size_t)(row0 + rl) * DFF;
#pragma unroll
                for (int ni = 0; ni < 2; ++ni) {
                    int col = n0 + wn * 32 + ni * 16 + (lane & 15);
                    float a = acc[0][mi][ni][i];
                    float b = acc[1][mi][ni][i];
                    float s = a / (1.0f + __expf(-a));
                    act[rp + col] = f2bf(s * b);
                }
            }
        }
}

// ---------------- GEMM2: y = act @ Wout^T, split-K=2, plain bf16 stores to ybuf ----------------
// tile: BM=128 x BN=128, BK=32, K=1024 per block
__global__ __launch_bounds__(256, 2)
void gemm2_kernel(const u16* __restrict__ act, const u16* __restrict__ woutbf,
                  u16* __restrict__ ybA, u16* __restrict__ ybB,
                  const int* __restrict__ offs) {
    int e = blockIdx.z >> 1;
    int kc = blockIdx.z & 1;
    int cnt = offs[e + 1] - offs[e];
    int mt = blockIdx.y;
    if (mt * 128 >= cnt) return;
    int row0 = offs[e] + mt * 128;
    int n0 = blockIdx.x * 128;
    const u16* wb = woutbf + (size_t)e * DMODEL * DFF;

    __shared__ u16 lsA[128 * 32];
    __shared__ u16 lsB[128 * 32];

    int tid = threadIdx.x, lane = tid & 63, wave = tid >> 6;
    int wm = wave >> 1, wn = wave & 1;

    f32x4 acc[4][4];
    f32x4 zero = {0.f, 0.f, 0.f, 0.f};
#pragma unroll
    for (int mi = 0; mi < 4; ++mi)
#pragma unroll
        for (int ni = 0; ni < 4; ++ni) acc[mi][ni] = zero;

    int s_row = lane >> 2;
    int s_col = src_cb(lane) * 8;

    for (int kk = kc * 32; kk < kc * 32 + 32; ++kk) {
        int k0 = kk * 32;
        const u16* ga = act + (size_t)(row0 + wave * 32 + s_row) * DFF + k0 + s_col;
        g2l16(ga, &lsA[(wave * 32) * 32]);
        g2l16(ga + 16 * DFF, &lsA[(wave * 32 + 16) * 32]);
        const u16* gb = wb + (size_t)(n0 + wave * 32 + s_row) * DFF + k0 + s_col;
        g2l16(gb, &lsB[(wave * 32) * 32]);
        g2l16(gb + 16 * DFF, &lsB[(wave * 32 + 16) * 32]);
        __syncthreads();
        bf16x8 afr[4];
#pragma unroll
        for (int mi = 0; mi < 4; ++mi)
            afr[mi] = *(const bf16x8*)&lsA[lds_idx(wm * 64 + mi * 16 + (lane & 15), lane >> 4)];
#pragma unroll
        for (int ni = 0; ni < 4; ++ni) {
            bf16x8 bfr = *(const bf16x8*)&lsB[lds_idx(wn * 64 + ni * 16 + (lane & 15), lane >> 4)];
#pragma unroll
            for (int mi = 0; mi < 4; ++mi)
                acc[mi][ni] = __builtin_amdgcn_mfma_f32_16x16x32_bf16(
                    afr[mi], bfr, acc[mi][ni], 0, 0, 0);
        }
        __syncthreads();
    }
    // epilogue: plain bf16 stores into per-slot y buffer (no atomics)
    u16* yb = kc ? ybB : ybA;
    int mmax = cnt - mt * 128;
#pragma unroll
    for (int mi = 0; mi < 4; ++mi)
#pragma unroll
        for (int i = 0; i < 4; ++i) {
            int rl = wm * 64 + mi * 16 + (lane >> 4) * 4 + i;
            if (rl < mmax) {
                u16* yrow = yb + (size_t)(row0 + rl) * DMODEL;
#pragma unroll
                for (int ni = 0; ni < 4; ++ni) {
                    int col = n0 + wn * 64 + ni * 16 + (lane & 15);
                    yrow[col] = f2bf(acc[mi][ni][i]);
                }
            }
        }
}

// ---------------- combine: out[t] = g0*(y0a+y0b) + g1*(y1a+y1b) ----------------
__global__ void combine_kernel(const u16* __restrict__ ybA, const u16* __restrict__ ybB,
                               const int* __restrict__ inv, const float* __restrict__ tok_gate,
                               float* __restrict__ out) {
    int t = blockIdx.x;
    int tid = threadIdx.x;                // 256
    __shared__ int sr0, sr1;
    __shared__ float sg0, sg1;
    if (tid == 0) {
        sr0 = inv[t * 2];  sr1 = inv[t * 2 + 1];
        sg0 = tok_gate[t * 2];  sg1 = tok_gate[t * 2 + 1];
    }
    __syncthreads();
    int d = tid * 4;
    u16x4 a0 = *(const u16x4*)(ybA + (size_t)sr0 * DMODEL + d);
    u16x4 b0 = *(const u16x4*)(ybB + (size_t)sr0 * DMODEL + d);
    u16x4 a1 = *(const u16x4*)(ybA + (size_t)sr1 * DMODEL + d);
    u16x4 b1 = *(const u16x4*)(ybB + (size_t)sr1 * DMODEL + d);
    float4 o;
    o.x = sg0 * (bf2f(a0.x) + bf2f(b0.x)) + sg1 * (bf2f(a1.x) + bf2f(b1.x));
    o.y = sg0 * (bf2f(a0.y) + bf2f(b0.y)) + sg1 * (bf2f(a1.y) + bf2f(b1.y));
    o.z = sg0 * (bf2f(a0.z) + bf2f(b0.z)) + sg1 * (bf2f(a1.z) + bf2f(b1.z));
    o.w = sg0 * (bf2f(a0.w) + bf2f(b0.w)) + sg1 * (bf2f(a1.w) + bf2f(b1.w));
    *(float4*)(out + (size_t)t * DMODEL + d) = o;
}

// ---------------- launch ----------------
extern "C" void kernel_launch(void* const* d_in, const int* in_sizes, int n_in,
                              void* d_out, int out_size, void* d_ws, size_t ws_size,
                              hipStream_t stream) {
    const float* x    = (const float*)d_in[0];   // [4096, 1024]
    const float* rw   = (const float*)d_in[1];   // [8, 1024]
    const float* win  = (const float*)d_in[2];   // [8, 4096, 1024]
    const float* wout = (const float*)d_in[3];   // [8, 1024, 2048]
    float* out    = (float*)d_out;               // [4096, 1024]
    float* logits = out + (size_t)N_TOK * DMODEL; // [4096, 8]

    char* ws = (char*)d_ws;
    size_t o = 0;
    auto alloc = [&](size_t bytes) -> void* {
        void* p = ws + o;
        o = (o + bytes + 255) & ~(size_t)255;
        return p;
    };
    u16*   Abf      = (u16*)  alloc((size_t)ROWS_PAD * DMODEL * 2);        // 17.0 MB
    u16*   actbuf   = (u16*)  alloc((size_t)ROWS_PAD * DFF * 2);           // 34.1 MB
    u16*   winbf    = (u16*)  alloc((size_t)N_EXP * 2 * DFF * DMODEL * 2); // 67.1 MB
    u16*   woutbf   = (u16*)  alloc((size_t)N_EXP * DMODEL * DFF * 2);     // 33.6 MB
    u16*   ybA      = (u16*)  alloc((size_t)ROWS_PAD * DMODEL * 2);        // 17.0 MB
    u16*   ybB      = (u16*)  alloc((size_t)ROWS_PAD * DMODEL * 2);        // 17.0 MB
    int*   offs     = (int*)  alloc(16 * 4);
    int*   cursor   = (int*)  alloc(N_EXP * 4);
    int*   inv      = (int*)  alloc(N_SLOTS * 4);
    int*   tok_exp  = (int*)  alloc(N_SLOTS * 4);
    float* tok_gate = (float*)alloc(N_SLOTS * 4);
    (void)ws_size; (void)in_sizes; (void)n_in; (void)out_size;

    cvt_kernel<<<(WIN_V8 + WOUT_V8) / 256, 256, 0, stream>>>(
        (const float4*)win, (const float4*)wout, (u16x8*)winbf, (u16x8*)woutbf);
    router_kernel<<<N_TOK, 64, 0, stream>>>(x, rw, logits, tok_exp, tok_gate);
    scan_kernel<<<1, 256, 0, stream>>>(tok_exp, offs, cursor);
    gather_kernel<<<N_SLOTS, 256, 0, stream>>>(x, tok_exp, offs, cursor, Abf, inv);
    gemm1_kernel<<<dim3(DFF / 64, MT_MAX, N_EXP), 256, 0, stream>>>(Abf, winbf, actbuf, offs);
    gemm2_kernel<<<dim3(DMODEL / 128, MT_MAX, N_EXP * 2), 256, 0, stream>>>(actbuf, woutbf,
                                                                            ybA, ybB, offs);
    combine_kernel<<<N_TOK, 256, 0, stream>>>(ybA, ybB, inv, tok_gate, out);
}